// Round 1
// baseline (325.292 us; speedup 1.0000x reference)
//
#include <hip/hip_runtime.h>

#define B_ 256
#define T_ 168
#define C_ 1024
#define H_ 24

// d_ws layout (floats): W[t*24 + k] for t in [0,168), k in [0,24); beta[k] at [168*24 + k]
// Total: 168*24 + 24 = 4056 floats = 16,224 bytes.

// One block. Thread t < 168 computes the whole column W[.][t] locally
// (W[k][t] depends only on W[j][t] for j<k -- same t, no cross-thread deps).
// Thread 168 computes beta.
__global__ __launch_bounds__(192) void ar_precompute(const float* __restrict__ w,
                                                     const float* __restrict__ bias,
                                                     float* __restrict__ ws) {
    __shared__ float lw[T_];
    const int t = threadIdx.x;
    if (t < T_) lw[t] = w[t];
    __syncthreads();
    if (t < T_) {
        float col[H_];
        #pragma unroll
        for (int k = 0; k < H_; ++k) {
            float v = (t >= k) ? lw[t - k] : 0.0f;
            #pragma unroll
            for (int j = 0; j < k; ++j)
                v += lw[T_ - k + j] * col[j];
            col[k] = v;
        }
        #pragma unroll
        for (int k = 0; k < H_; ++k)
            ws[t * H_ + k] = col[k];
    } else if (t == T_) {
        float bv = bias[0];
        float beta[H_];
        #pragma unroll
        for (int k = 0; k < H_; ++k) {
            float v = bv;
            #pragma unroll
            for (int j = 0; j < k; ++j)
                v += lw[T_ - k + j] * beta[j];
            beta[k] = v;
        }
        #pragma unroll
        for (int k = 0; k < H_; ++k)
            ws[T_ * H_ + k] = beta[k];
    }
}

// out[b,k,c] = beta[k] + sum_t W[k][t] * y[b,t,c]
// One thread per (b,c). grid = (C/256, B), block = 256.
__global__ __launch_bounds__(256) void ar_main(const float* __restrict__ y,
                                               const float* __restrict__ ws,
                                               float* __restrict__ out) {
    const int c = blockIdx.x * 256 + threadIdx.x;
    const int b = blockIdx.y;
    const float* __restrict__ yp = y + (size_t)b * (size_t)(T_ * C_) + c;
    const float* __restrict__ beta = ws + T_ * H_;

    float acc[H_];
    #pragma unroll
    for (int k = 0; k < H_; ++k) acc[k] = beta[k];   // uniform load -> s_load

    #pragma unroll 4
    for (int t = 0; t < T_; ++t) {
        const float yv = yp[(size_t)t * C_];          // coalesced across lanes
        const float4* __restrict__ w4 = (const float4*)(ws + t * H_);
        #pragma unroll
        for (int q = 0; q < H_ / 4; ++q) {            // uniform addr -> s_load_dwordx4
            const float4 wv = w4[q];
            acc[4 * q + 0] += wv.x * yv;
            acc[4 * q + 1] += wv.y * yv;
            acc[4 * q + 2] += wv.z * yv;
            acc[4 * q + 3] += wv.w * yv;
        }
    }

    float* __restrict__ op = out + ((size_t)b * H_) * C_ + c;
    #pragma unroll
    for (int k = 0; k < H_; ++k)
        op[(size_t)k * C_] = acc[k];                  // coalesced across lanes
}

extern "C" void kernel_launch(void* const* d_in, const int* in_sizes, int n_in,
                              void* d_out, int out_size, void* d_ws, size_t ws_size,
                              hipStream_t stream) {
    // inputs: 0=x (unused), 1=y (B,T,C), 2=w (1,168), 3=b (1,)
    const float* y    = (const float*)d_in[1];
    const float* w    = (const float*)d_in[2];
    const float* bias = (const float*)d_in[3];
    float* out = (float*)d_out;
    float* ws  = (float*)d_ws;

    ar_precompute<<<1, 192, 0, stream>>>(w, bias, ws);
    ar_main<<<dim3(C_ / 256, B_), 256, 0, stream>>>(y, ws, out);
}